// Round 1
// baseline (49046.317 us; speedup 1.0000x reference)
//
#include <hip/hip_runtime.h>
#include <math.h>

// ---------------------------------------------------------------------------
// TransformerTinyRecursiveModel — Round 1: correct fp32 baseline.
// Structure: 1 wave processes 4 rows (weight fetch amortized x4).
// Exploits: k0/v0 step-invariant; only token-2 query needed (o[:,0:2,:] dead).
// ---------------------------------------------------------------------------

constexpr int E      = 64;
constexpr int FF     = 128;
constexpr int STEPS  = 16;
constexpr int INDIM  = 200;

constexpr int RPW = 4;            // rows per wave
constexpr int WPB = 4;            // waves per block
constexpr int RPB = RPW * WPB;    // 16 rows per block

// LDS arena offsets (floats). vec64 buffers are [RPB][64].
constexpr int OFF_Y    = 0;
constexpr int OFF_Z    = 1024;
constexpr int OFF_K0   = 2048;
constexpr int OFF_V0   = 3072;
constexpr int OFF_RES  = 4096;
constexpr int OFF_T    = 5120;
constexpr int OFF_XP   = 6144;
constexpr int OFF_Q2   = 7168;
constexpr int OFF_K1   = 8192;
constexpr int OFF_V1   = 9216;
constexpr int OFF_K2   = 10240;
constexpr int OFF_V2   = 11264;
constexpr int OFF_O2   = 12288;
constexpr int OFF_H    = 13312;                 // [RPB][128]
constexpr int ARENA_F  = OFF_H + RPB * FF;      // 15360 floats = 61.4 KB
constexpr int OFF_XBUF = OFF_Q2;                // [RPB][200] aliases Q2..O2 (prologue only)

struct Params {
  const float *x, *W_in, *b_in, *g_in, *be_in;
  const float *z_in_w, *z_in_b, *z_out_w, *z_out_b;
  const float *z_ffn_w1, *z_ffn_b1, *z_ffn_w2, *z_ffn_b2;
  const float *zn1_g, *zn1_b, *zn2_g, *zn2_b;
  const float *y_in_w, *y_in_b, *y_out_w, *y_out_b;
  const float *y_ffn_w1, *y_ffn_b1, *y_ffn_w2, *y_ffn_b2;
  const float *yn1_g, *yn1_b, *yn2_g, *yn2_b;
  const float *W_out, *b_out;
  float *out;
  int nrows;
};

__device__ __forceinline__ float wredsum(float v) {
#pragma unroll
  for (int m = 32; m >= 1; m >>= 1) v += __shfl_xor(v, m, 64);
  return v;
}
// reduce within each 16-lane head group
__device__ __forceinline__ float hredsum(float v) {
#pragma unroll
  for (int m = 8; m >= 1; m >>= 1) v += __shfl_xor(v, m, 64);
  return v;
}
__device__ __forceinline__ float gelu_exact(float x) {
  return 0.5f * x * (1.0f + erff(x * 0.70710678118654752f));
}
// layernorm: lane j holds element j of the row; returns normalized value
__device__ __forceinline__ float lnorm(float pre, const float* __restrict__ g,
                                       const float* __restrict__ b, int j) {
  float m = wredsum(pre) * (1.0f / 64.0f);
  float d = pre - m;
  float v = wredsum(d * d) * (1.0f / 64.0f);
  return d * rsqrtf(v + 1e-5f) * g[j] + b[j];
}

// 4 simultaneous dot products (4 rows, stride K in LDS) vs one weight row.
template <int K>
__device__ __forceinline__ void mv4(const float* __restrict__ wrow,
                                    const float* __restrict__ in,
                                    float bias, float out[RPW]) {
  float a0 = bias, a1 = bias, a2 = bias, a3 = bias;
#pragma unroll
  for (int i = 0; i < K; i += 4) {
    const float4 w = *(const float4*)(wrow + i);
    float4 q;
    q = *(const float4*)(in + 0 * K + i);
    a0 = fmaf(w.x, q.x, fmaf(w.y, q.y, fmaf(w.z, q.z, fmaf(w.w, q.w, a0))));
    q = *(const float4*)(in + 1 * K + i);
    a1 = fmaf(w.x, q.x, fmaf(w.y, q.y, fmaf(w.z, q.z, fmaf(w.w, q.w, a1))));
    q = *(const float4*)(in + 2 * K + i);
    a2 = fmaf(w.x, q.x, fmaf(w.y, q.y, fmaf(w.z, q.z, fmaf(w.w, q.w, a2))));
    q = *(const float4*)(in + 3 * K + i);
    a3 = fmaf(w.x, q.x, fmaf(w.y, q.y, fmaf(w.z, q.z, fmaf(w.w, q.w, a3))));
  }
  out[0] = a0; out[1] = a1; out[2] = a2; out[3] = a3;
}

__global__ __launch_bounds__(256, 2) void trm_kernel(Params p) {
  __shared__ float arena[ARENA_F];
  const int tid  = threadIdx.x;
  const int wave = tid >> 6;
  const int j    = tid & 63;           // lane == element index within a row
  const int rb0  = wave * RPW;
  const int row0 = blockIdx.x * RPB + rb0;

  float* Y   = arena + OFF_Y   + rb0 * E;
  float* Z   = arena + OFF_Z   + rb0 * E;
  float* K0  = arena + OFF_K0  + rb0 * E;
  float* V0  = arena + OFF_V0  + rb0 * E;
  float* RES = arena + OFF_RES + rb0 * E;
  float* T   = arena + OFF_T   + rb0 * E;
  float* XP  = arena + OFF_XP  + rb0 * E;
  float* Q2  = arena + OFF_Q2  + rb0 * E;
  float* K1  = arena + OFF_K1  + rb0 * E;
  float* V1  = arena + OFF_V1  + rb0 * E;
  float* K2  = arena + OFF_K2  + rb0 * E;
  float* V2  = arena + OFF_V2  + rb0 * E;
  float* O2  = arena + OFF_O2  + rb0 * E;
  float* HB  = arena + OFF_H   + rb0 * FF;
  float* XB  = arena + OFF_XBUF + rb0 * INDIM;

  // ---- stage x rows into LDS (50 float4 per row) ----
  for (int t = j; t < RPW * 50; t += 64) {
    int r = t / 50, c = t % 50;
    int rr = row0 + r;
    if (rr < p.nrows)
      *(float4*)(XB + r * INDIM + c * 4) =
          *(const float4*)(p.x + (size_t)rr * INDIM + c * 4);
  }
  __syncthreads();

  float acc[RPW], acc2[RPW];

  // ---- x_proj = gelu(ln(x @ W_in^T + b_in)) ----
  mv4<INDIM>(p.W_in + j * INDIM, XB, p.b_in[j], acc);
#pragma unroll
  for (int r = 0; r < RPW; r++)
    XP[r * E + j] = gelu_exact(lnorm(acc[r], p.g_in, p.be_in, j));
  __syncthreads();

  // ---- k0, v0 (step-invariant), init y = z = 0 ----
  mv4<E>(p.z_in_w + (64 + j) * E, XP, p.z_in_b[64 + j], acc);
  mv4<E>(p.z_in_w + (128 + j) * E, XP, p.z_in_b[128 + j], acc2);
#pragma unroll
  for (int r = 0; r < RPW; r++) {
    K0[r * E + j] = acc[r];
    V0[r * E + j] = acc2[r];
    Y[r * E + j] = 0.0f;
    Z[r * E + j] = 0.0f;
  }
  __syncthreads();

  for (int s = 0; s < STEPS; s++) {
    // phase 1: q2 (from z), k2/v2 (from z), k1/v1 (from y)
    mv4<E>(p.z_in_w + j * E, Z, p.z_in_b[j], acc);
#pragma unroll
    for (int r = 0; r < RPW; r++) Q2[r * E + j] = acc[r];
    mv4<E>(p.z_in_w + (64 + j) * E, Z, p.z_in_b[64 + j], acc);
    mv4<E>(p.z_in_w + (128 + j) * E, Z, p.z_in_b[128 + j], acc2);
#pragma unroll
    for (int r = 0; r < RPW; r++) { K2[r * E + j] = acc[r]; V2[r * E + j] = acc2[r]; }
    mv4<E>(p.z_in_w + (64 + j) * E, Y, p.z_in_b[64 + j], acc);
    mv4<E>(p.z_in_w + (128 + j) * E, Y, p.z_in_b[128 + j], acc2);
#pragma unroll
    for (int r = 0; r < RPW; r++) { K1[r * E + j] = acc[r]; V1[r * E + j] = acc2[r]; }
    __syncthreads();

    // phase 2: attention for token 2 (per head = 16-lane group)
#pragma unroll
    for (int r = 0; r < RPW; r++) {
      float qv = Q2[r * E + j];
      float s0 = hredsum(qv * K0[r * E + j]) * 0.25f;
      float s1 = hredsum(qv * K1[r * E + j]) * 0.25f;
      float s2 = hredsum(qv * K2[r * E + j]) * 0.25f;
      float mx = fmaxf(s0, fmaxf(s1, s2));
      float e0 = expf(s0 - mx), e1 = expf(s1 - mx), e2 = expf(s2 - mx);
      float inv = 1.0f / (e0 + e1 + e2);
      O2[r * E + j] =
          (e0 * V0[r * E + j] + e1 * V1[r * E + j] + e2 * V2[r * E + j]) * inv;
    }
    __syncthreads();

    // phase 3: o2 @ z_out^T + b, + z residual, LN1z
    mv4<E>(p.z_out_w + j * E, O2, p.z_out_b[j], acc);
    float zres[RPW];
#pragma unroll
    for (int r = 0; r < RPW; r++) {
      float pre = Z[r * E + j] + acc[r];
      zres[r] = lnorm(pre, p.zn1_g, p.zn1_b, j);
      RES[r * E + j] = zres[r];
    }
    __syncthreads();

    // phase 4: z-FFN layer 1 + gelu
    mv4<E>(p.z_ffn_w1 + j * E, RES, p.z_ffn_b1[j], acc);
    mv4<E>(p.z_ffn_w1 + (64 + j) * E, RES, p.z_ffn_b1[64 + j], acc2);
#pragma unroll
    for (int r = 0; r < RPW; r++) {
      HB[r * FF + j] = gelu_exact(acc[r]);
      HB[r * FF + 64 + j] = gelu_exact(acc2[r]);
    }
    __syncthreads();

    // phase 5: z-FFN layer 2 + residual + LN2z -> z2
    mv4<FF>(p.z_ffn_w2 + j * FF, HB, p.z_ffn_b2[j], acc);
#pragma unroll
    for (int r = 0; r < RPW; r++)
      Z[r * E + j] = lnorm(zres[r] + acc[r], p.zn2_g, p.zn2_b, j);
    __syncthreads();

    // phase 6: t = z2 @ Wv_y^T + bv_y  (Wv_y = y_in_w rows 128..191)
    mv4<E>(p.y_in_w + (128 + j) * E, Z, p.y_in_b[128 + j], acc);
#pragma unroll
    for (int r = 0; r < RPW; r++) T[r * E + j] = acc[r];
    __syncthreads();

    // phase 7: ca = t @ y_out^T + b, + y residual, LN1y
    mv4<E>(p.y_out_w + j * E, T, p.y_out_b[j], acc);
    float yres[RPW];
#pragma unroll
    for (int r = 0; r < RPW; r++) {
      float pre = Y[r * E + j] + acc[r];
      yres[r] = lnorm(pre, p.yn1_g, p.yn1_b, j);
      RES[r * E + j] = yres[r];
    }
    __syncthreads();

    // phase 8: y-FFN layer 1 + gelu
    mv4<E>(p.y_ffn_w1 + j * E, RES, p.y_ffn_b1[j], acc);
    mv4<E>(p.y_ffn_w1 + (64 + j) * E, RES, p.y_ffn_b1[64 + j], acc2);
#pragma unroll
    for (int r = 0; r < RPW; r++) {
      HB[r * FF + j] = gelu_exact(acc[r]);
      HB[r * FF + 64 + j] = gelu_exact(acc2[r]);
    }
    __syncthreads();

    // phase 9: y-FFN layer 2 + residual + LN2y -> y2
    mv4<FF>(p.y_ffn_w2 + j * FF, HB, p.y_ffn_b2[j], acc);
#pragma unroll
    for (int r = 0; r < RPW; r++)
      Y[r * E + j] = lnorm(yres[r] + acc[r], p.yn2_g, p.yn2_b, j);
    __syncthreads();
  }

  // ---- output: (y @ W_out^T + b_out)[:, 0] ----
  float wo = p.W_out[j];
  float bo = p.b_out[0];
#pragma unroll
  for (int r = 0; r < RPW; r++) {
    float s = wredsum(Y[r * E + j] * wo);
    int rr = row0 + r;
    if (j == 0 && rr < p.nrows) p.out[rr] = s + bo;
  }
}

extern "C" void kernel_launch(void* const* d_in, const int* in_sizes, int n_in,
                              void* d_out, int out_size, void* d_ws, size_t ws_size,
                              hipStream_t stream) {
  Params p;
  const float* const* in = (const float* const*)d_in;
  p.x        = in[0];  p.W_in     = in[1];  p.b_in     = in[2];
  p.g_in     = in[3];  p.be_in    = in[4];
  p.z_in_w   = in[5];  p.z_in_b   = in[6];
  p.z_out_w  = in[7];  p.z_out_b  = in[8];
  p.z_ffn_w1 = in[9];  p.z_ffn_b1 = in[10];
  p.z_ffn_w2 = in[11]; p.z_ffn_b2 = in[12];
  p.zn1_g    = in[13]; p.zn1_b    = in[14];
  p.zn2_g    = in[15]; p.zn2_b    = in[16];
  p.y_in_w   = in[17]; p.y_in_b   = in[18];
  p.y_out_w  = in[19]; p.y_out_b  = in[20];
  p.y_ffn_w1 = in[21]; p.y_ffn_b1 = in[22];
  p.y_ffn_w2 = in[23]; p.y_ffn_b2 = in[24];
  p.yn1_g    = in[25]; p.yn1_b    = in[26];
  p.yn2_g    = in[27]; p.yn2_b    = in[28];
  p.W_out    = in[29]; p.b_out    = in[30];
  p.out      = (float*)d_out;
  p.nrows    = in_sizes[0] / INDIM;

  int blocks = (p.nrows + RPB - 1) / RPB;
  hipLaunchKernelGGL(trm_kernel, dim3(blocks), dim3(256), 0, stream, p);
}

// Round 2
// 4815.211 us; speedup vs baseline: 10.1857x; 10.1857x over previous
//
#include <hip/hip_runtime.h>
#include <math.h>

// ---------------------------------------------------------------------------
// Round 2: MFMA bf16 rewrite.
//   D[m=out_feat][n=sample] = W * X^T via mfma_f32_16x16x32_bf16.
//   A-frags = weights, prepacked (bf16, frag-major) into d_ws by a prologue
//   kernel -> coalesced 1KB global loads, L1/L2 hot.
//   B-frags = activations, [sample][feat(+pad)] bf16 in per-wave private LDS
//   (stride 72/136 shorts -> 2-way bank aliasing only, which is free).
//   C stays in registers: LN / attention / gelu / residuals done on C-layout
//   (per sample: 16 feats in-lane x 4 quads -> 2 shuffles per reduction).
//   1 wave = 16 samples, no __syncthreads anywhere, 2 blocks/CU.
// ---------------------------------------------------------------------------

constexpr int STEPS = 16;
constexpr int INDIM = 200;

typedef __attribute__((ext_vector_type(8))) short bfrag8;   // 8 bf16 = 4 VGPR
typedef __attribute__((ext_vector_type(4))) float f32x4;
typedef __attribute__((ext_vector_type(4))) short s16x4;

// frag base indices inside d_ws (1 frag = 64 lanes * 16B = 1024 B = 512 shorts)
constexpr int FB_WIN  = 0;    // W_in: mt(4) x kt(7), f = mt*7+kt
constexpr int FB_ZQ   = 28;   // z_in_w rows   0..63 : mt*2+kt
constexpr int FB_ZK   = 36;   // z_in_w rows  64..127
constexpr int FB_ZV   = 44;   // z_in_w rows 128..191
constexpr int FB_ZOUT = 52;
constexpr int FB_ZF1  = 60;   // 128x64: mt(8)x kt(2)
constexpr int FB_ZF2  = 76;   // 64x128: mt(4)x kt(4)
constexpr int FB_YV   = 92;   // y_in_w rows 128..191
constexpr int FB_YOUT = 100;
constexpr int FB_YF1  = 108;
constexpr int FB_YF2  = 124;
constexpr int NFRAG   = 140;  // 143,360 B of workspace

// per-wave LDS buffers (units: shorts). stride 72 (64-feat) / 136 (128-feat)
constexpr int S64  = 72;
constexpr int S128 = 136;
constexpr int O_XP = 0;
constexpr int O_Y  = 1152;
constexpr int O_Z  = 2304;
constexpr int O_K0 = 3456;
constexpr int O_V0 = 4608;
constexpr int O_T  = 5760;
constexpr int O_H  = 6912;             // [16][136]
constexpr int WAVE_SH = 9088;          // shorts per wave = 18,176 B

struct Params {
  const float *x, *W_in, *b_in, *g_in, *be_in;
  const float *z_in_w, *z_in_b, *z_out_w, *z_out_b;
  const float *z_ffn_w1, *z_ffn_b1, *z_ffn_w2, *z_ffn_b2;
  const float *zn1_g, *zn1_b, *zn2_g, *zn2_b;
  const float *y_in_w, *y_in_b, *y_out_w, *y_out_b;
  const float *y_ffn_w1, *y_ffn_b1, *y_ffn_w2, *y_ffn_b2;
  const float *yn1_g, *yn1_b, *yn2_g, *yn2_b;
  const float *W_out, *b_out;
  float *out;
  int nrows;
};

// ---- bf16 helpers (bit-level, RNE) ----
__device__ __forceinline__ ushort f2bf(float f) {
  uint u = __float_as_uint(f);
  u += 0x7FFFu + ((u >> 16) & 1u);
  return (ushort)(u >> 16);
}
__device__ __forceinline__ float bf2f(ushort h) {
  return __uint_as_float(((uint)h) << 16);
}

__device__ __forceinline__ float dot4(f32x4 a, f32x4 b) {
  return a.x * b.x + a.y * b.y + a.z * b.z + a.w * b.w;
}

// store one C quad (4 fp32 -> 4 bf16, ds_write_b64) at [sample][mt*16+q*4]
__device__ __forceinline__ void stc(short* buf, int stride, int mt, int q,
                                    int s, f32x4 c) {
  s16x4 v;
  v.x = (short)f2bf(c.x); v.y = (short)f2bf(c.y);
  v.z = (short)f2bf(c.z); v.w = (short)f2bf(c.w);
  *(s16x4*)(buf + s * stride + mt * 16 + q * 4) = v;
}
// read back one C quad as floats (ds_read_b64)
__device__ __forceinline__ f32x4 ldc4(const short* buf, int stride, int mt,
                                      int q, int s) {
  s16x4 v = *(const s16x4*)(buf + s * stride + mt * 16 + q * 4);
  f32x4 f;
  f.x = bf2f((ushort)v.x); f.y = bf2f((ushort)v.y);
  f.z = bf2f((ushort)v.z); f.w = bf2f((ushort)v.w);
  return f;
}

// one layer: c[mt] = W * X^T + bias, MT out-tiles, KT k-tiles
template <int MT, int KT>
__device__ __forceinline__ void layerN(const short* in, int stride,
                                       const ushort* wf, int fbase,
                                       const float* bias, f32x4* c,
                                       int lane, int q, int s) {
  bfrag8 bf[KT];
#pragma unroll
  for (int kt = 0; kt < KT; ++kt)
    bf[kt] = *(const bfrag8*)(in + s * stride + kt * 32 + q * 8);
#pragma unroll
  for (int mt = 0; mt < MT; ++mt)
    c[mt] = *(const f32x4*)(bias + mt * 16 + q * 4);
#pragma unroll
  for (int mt = 0; mt < MT; ++mt) {
#pragma unroll
    for (int kt = 0; kt < KT; ++kt) {
      bfrag8 af =
          *(const bfrag8*)(wf + (size_t)(fbase + mt * KT + kt) * 512 + lane * 8);
      c[mt] = __builtin_amdgcn_mfma_f32_16x16x32_bf16(af, bf[kt], c[mt], 0, 0, 0);
    }
  }
}

// layernorm on C-layout regs: 64 feats of one sample live in (4 regs x MT=4
// tiles) in-lane plus lanes s+16k. Two xor-shuffles complete the reduction.
__device__ __forceinline__ void lnorm_c(f32x4 c[4], const float* g,
                                        const float* b, int q) {
  float sm = 0.f;
#pragma unroll
  for (int mt = 0; mt < 4; ++mt) sm += c[mt].x + c[mt].y + c[mt].z + c[mt].w;
  sm += __shfl_xor(sm, 16); sm += __shfl_xor(sm, 32);
  float mean = sm * (1.f / 64.f);
  float vs = 0.f;
#pragma unroll
  for (int mt = 0; mt < 4; ++mt) {
    f32x4 d = c[mt];
    d.x -= mean; d.y -= mean; d.z -= mean; d.w -= mean;
    c[mt] = d;
    vs += d.x * d.x + d.y * d.y + d.z * d.z + d.w * d.w;
  }
  vs += __shfl_xor(vs, 16); vs += __shfl_xor(vs, 32);
  float rs = rsqrtf(vs * (1.f / 64.f) + 1e-5f);
#pragma unroll
  for (int mt = 0; mt < 4; ++mt) {
    f32x4 g4 = *(const f32x4*)(g + mt * 16 + q * 4);
    f32x4 b4 = *(const f32x4*)(b + mt * 16 + q * 4);
    f32x4 v = c[mt];
    v.x = v.x * rs * g4.x + b4.x; v.y = v.y * rs * g4.y + b4.y;
    v.z = v.z * rs * g4.z + b4.z; v.w = v.w * rs * g4.w + b4.w;
    c[mt] = v;
  }
}

// exact-grade gelu: erf via Abramowitz-Stegun 7.1.26 (|err| <= 1.5e-7)
__device__ __forceinline__ float gelu1(float x) {
  float ax = fabsf(x) * 0.70710678118654752f;
  float t = __builtin_amdgcn_rcpf(1.0f + 0.3275911f * ax);
  float poly =
      ((((1.061405429f * t - 1.453152027f) * t + 1.421413741f) * t -
        0.284496736f) * t + 0.254829592f) * t;
  float e = __expf(-ax * ax);
  float erfv = copysignf(1.0f - poly * e, x);
  return 0.5f * x * (1.0f + erfv);
}

// ---------------------------------------------------------------------------
// prologue: repack weights into A-frag order (bf16) in workspace
// ---------------------------------------------------------------------------
__global__ void prepack_kernel(Params p, ushort* wf) {
  int f = blockIdx.x;
  int lane = threadIdx.x;
  int q = lane >> 4, r = lane & 15;

  const float* src; int K, mt, kt, l;
  if (f < 28)        { src = p.W_in;                K = 200; mt = f / 7;  kt = f % 7; }
  else if (f < 36)   { l = f - 28;  src = p.z_in_w;            K = 64;  mt = l / 2; kt = l % 2; }
  else if (f < 44)   { l = f - 36;  src = p.z_in_w + 64 * 64;  K = 64;  mt = l / 2; kt = l % 2; }
  else if (f < 52)   { l = f - 44;  src = p.z_in_w + 128 * 64; K = 64;  mt = l / 2; kt = l % 2; }
  else if (f < 60)   { l = f - 52;  src = p.z_out_w;           K = 64;  mt = l / 2; kt = l % 2; }
  else if (f < 76)   { l = f - 60;  src = p.z_ffn_w1;          K = 64;  mt = l / 2; kt = l % 2; }
  else if (f < 92)   { l = f - 76;  src = p.z_ffn_w2;          K = 128; mt = l / 4; kt = l % 4; }
  else if (f < 100)  { l = f - 92;  src = p.y_in_w + 128 * 64; K = 64;  mt = l / 2; kt = l % 2; }
  else if (f < 108)  { l = f - 100; src = p.y_out_w;           K = 64;  mt = l / 2; kt = l % 2; }
  else if (f < 124)  { l = f - 108; src = p.y_ffn_w1;          K = 64;  mt = l / 2; kt = l % 2; }
  else               { l = f - 124; src = p.y_ffn_w2;          K = 128; mt = l / 4; kt = l % 4; }

  int row = mt * 16 + r;
  int col = kt * 32 + q * 8;
  bfrag8 o;
#pragma unroll
  for (int j = 0; j < 8; ++j) {
    int cc = col + j;
    float v = (cc < K) ? src[(size_t)row * K + cc] : 0.0f;
    o[j] = (short)f2bf(v);
  }
  *(bfrag8*)(wf + (size_t)f * 512 + lane * 8) = o;
}

// ---------------------------------------------------------------------------
// main kernel
// ---------------------------------------------------------------------------
__global__ __launch_bounds__(256, 2) void trm_mfma_kernel(Params p,
                                                          const ushort* wf) {
  __shared__ __align__(16) short arena[4 * WAVE_SH];
  const int tid = threadIdx.x;
  const int wave = tid >> 6, lane = tid & 63;
  const int q = lane >> 4, s = lane & 15;
  short* WA = arena + wave * WAVE_SH;
  short *XP = WA + O_XP, *Yb = WA + O_Y, *Zb = WA + O_Z;
  short *K0 = WA + O_K0, *V0 = WA + O_V0, *Tb = WA + O_T, *Hb = WA + O_H;

  const int row0 = blockIdx.x * 64 + wave * 16;
  int row = row0 + s;
  if (row >= p.nrows) row = p.nrows - 1;   // clamp (full grid anyway)

  // ---- x_proj = gelu(ln(x @ W_in^T + b_in)) ; B-frags straight from global x
  {
    const float* xr = p.x + (size_t)row * INDIM;
    bfrag8 xb[7];
#pragma unroll
    for (int kt = 0; kt < 7; ++kt) {
      int k0i = kt * 32 + q * 8;
      bfrag8 t;
      if (kt < 6 || q == 0) {
        f32x4 lo = *(const f32x4*)(xr + k0i);
        f32x4 hi = *(const f32x4*)(xr + k0i + 4);
        t[0] = (short)f2bf(lo.x); t[1] = (short)f2bf(lo.y);
        t[2] = (short)f2bf(lo.z); t[3] = (short)f2bf(lo.w);
        t[4] = (short)f2bf(hi.x); t[5] = (short)f2bf(hi.y);
        t[6] = (short)f2bf(hi.z); t[7] = (short)f2bf(hi.w);
      } else {
#pragma unroll
        for (int j = 0; j < 8; ++j) t[j] = 0;
      }
      xb[kt] = t;
    }
    f32x4 c[4];
#pragma unroll
    for (int mt = 0; mt < 4; ++mt)
      c[mt] = *(const f32x4*)(p.b_in + mt * 16 + q * 4);
#pragma unroll
    for (int mt = 0; mt < 4; ++mt)
#pragma unroll
      for (int kt = 0; kt < 7; ++kt) {
        bfrag8 af =
            *(const bfrag8*)(wf + (size_t)(FB_WIN + mt * 7 + kt) * 512 + lane * 8);
        c[mt] = __builtin_amdgcn_mfma_f32_16x16x32_bf16(af, xb[kt], c[mt], 0, 0, 0);
      }
    lnorm_c(c, p.g_in, p.be_in, q);
#pragma unroll
    for (int mt = 0; mt < 4; ++mt) {
      c[mt].x = gelu1(c[mt].x); c[mt].y = gelu1(c[mt].y);
      c[mt].z = gelu1(c[mt].z); c[mt].w = gelu1(c[mt].w);
      stc(XP, S64, mt, q, s, c[mt]);
    }
  }

  // ---- k0/v0 (step-invariant), y=z=0
  {
    f32x4 ck[4], cv[4];
    layerN<4, 2>(XP, S64, wf, FB_ZK, p.z_in_b + 64, ck, lane, q, s);
    layerN<4, 2>(XP, S64, wf, FB_ZV, p.z_in_b + 128, cv, lane, q, s);
    s16x4 z4; z4.x = 0; z4.y = 0; z4.z = 0; z4.w = 0;
#pragma unroll
    for (int mt = 0; mt < 4; ++mt) {
      stc(K0, S64, mt, q, s, ck[mt]);
      stc(V0, S64, mt, q, s, cv[mt]);
      *(s16x4*)(Yb + s * S64 + mt * 16 + q * 4) = z4;
      *(s16x4*)(Zb + s * S64 + mt * 16 + q * 4) = z4;
    }
  }

  // ---- 16 recursive steps
  for (int st = 0; st < STEPS; ++st) {
    f32x4 q2[4], k2[4], v2[4], k1[4], v1[4];
    layerN<4, 2>(Zb, S64, wf, FB_ZQ, p.z_in_b, q2, lane, q, s);
    layerN<4, 2>(Zb, S64, wf, FB_ZK, p.z_in_b + 64, k2, lane, q, s);
    layerN<4, 2>(Zb, S64, wf, FB_ZV, p.z_in_b + 128, v2, lane, q, s);
    layerN<4, 2>(Yb, S64, wf, FB_ZK, p.z_in_b + 64, k1, lane, q, s);
    layerN<4, 2>(Yb, S64, wf, FB_ZV, p.z_in_b + 128, v1, lane, q, s);

    // attention (head h == M-tile h); softmax over tokens {x_proj, y, z}
#pragma unroll
    for (int mt = 0; mt < 4; ++mt) {
      f32x4 k0t = ldc4(K0, S64, mt, q, s);
      f32x4 v0t = ldc4(V0, S64, mt, q, s);
      float a0 = dot4(q2[mt], k0t);
      float a1 = dot4(q2[mt], k1[mt]);
      float a2 = dot4(q2[mt], k2[mt]);
      a0 += __shfl_xor(a0, 16); a0 += __shfl_xor(a0, 32);
      a1 += __shfl_xor(a1, 16); a1 += __shfl_xor(a1, 32);
      a2 += __shfl_xor(a2, 16); a2 += __shfl_xor(a2, 32);
      a0 *= 0.25f; a1 *= 0.25f; a2 *= 0.25f;
      float mx = fmaxf(a0, fmaxf(a1, a2));
      float e0 = __expf(a0 - mx), e1 = __expf(a1 - mx), e2 = __expf(a2 - mx);
      float inv = __builtin_amdgcn_rcpf(e0 + e1 + e2);
      f32x4 o;
      o.x = (v0t.x * e0 + v1[mt].x * e1 + v2[mt].x * e2) * inv;
      o.y = (v0t.y * e0 + v1[mt].y * e1 + v2[mt].y * e2) * inv;
      o.z = (v0t.z * e0 + v1[mt].z * e1 + v2[mt].z * e2) * inv;
      o.w = (v0t.w * e0 + v1[mt].w * e1 + v2[mt].w * e2) * inv;
      stc(Tb, S64, mt, q, s, o);
    }

    // z branch: z_res = ln(z + o2 @ z_out^T + b), z2 = ln(z_res + ffn(z_res))
    f32x4 zr[4];
    layerN<4, 2>(Tb, S64, wf, FB_ZOUT, p.z_out_b, zr, lane, q, s);
#pragma unroll
    for (int mt = 0; mt < 4; ++mt) {
      f32x4 zp = ldc4(Zb, S64, mt, q, s);
      zr[mt].x += zp.x; zr[mt].y += zp.y; zr[mt].z += zp.z; zr[mt].w += zp.w;
    }
    lnorm_c(zr, p.zn1_g, p.zn1_b, q);
#pragma unroll
    for (int mt = 0; mt < 4; ++mt) stc(Tb, S64, mt, q, s, zr[mt]);

    f32x4 h8[8];
    layerN<8, 2>(Tb, S64, wf, FB_ZF1, p.z_ffn_b1, h8, lane, q, s);
#pragma unroll
    for (int mt = 0; mt < 8; ++mt) {
      h8[mt].x = gelu1(h8[mt].x); h8[mt].y = gelu1(h8[mt].y);
      h8[mt].z = gelu1(h8[mt].z); h8[mt].w = gelu1(h8[mt].w);
      stc(Hb, S128, mt, q, s, h8[mt]);
    }
    f32x4 z2[4];
    layerN<4, 4>(Hb, S128, wf, FB_ZF2, p.z_ffn_b2, z2, lane, q, s);
#pragma unroll
    for (int mt = 0; mt < 4; ++mt) {
      z2[mt].x += zr[mt].x; z2[mt].y += zr[mt].y;
      z2[mt].z += zr[mt].z; z2[mt].w += zr[mt].w;
    }
    lnorm_c(z2, p.zn2_g, p.zn2_b, q);
#pragma unroll
    for (int mt = 0; mt < 4; ++mt) stc(Zb, S64, mt, q, s, z2[mt]);

    // y branch: ca = (z2 @ Wv_y^T + bv_y) @ y_out^T + b
    f32x4 t4[4];
    layerN<4, 2>(Zb, S64, wf, FB_YV, p.y_in_b + 128, t4, lane, q, s);
#pragma unroll
    for (int mt = 0; mt < 4; ++mt) stc(Tb, S64, mt, q, s, t4[mt]);

    f32x4 yr[4];
    layerN<4, 2>(Tb, S64, wf, FB_YOUT, p.y_out_b, yr, lane, q, s);
#pragma unroll
    for (int mt = 0; mt < 4; ++mt) {
      f32x4 yp = ldc4(Yb, S64, mt, q, s);
      yr[mt].x += yp.x; yr[mt].y += yp.y; yr[mt].z += yp.z; yr[mt].w += yp.w;
    }
    lnorm_c(yr, p.yn1_g, p.yn1_b, q);
#pragma unroll
    for (int mt = 0; mt < 4; ++mt) stc(Tb, S64, mt, q, s, yr[mt]);

    layerN<8, 2>(Tb, S64, wf, FB_YF1, p.y_ffn_b1, h8, lane, q, s);
#pragma unroll
    for (int mt = 0; mt < 8; ++mt) {
      h8[mt].x = gelu1(h8[mt].x); h8[mt].y = gelu1(h8[mt].y);
      h8[mt].z = gelu1(h8[mt].z); h8[mt].w = gelu1(h8[mt].w);
      stc(Hb, S128, mt, q, s, h8[mt]);
    }
    f32x4 y2[4];
    layerN<4, 4>(Hb, S128, wf, FB_YF2, p.y_ffn_b2, y2, lane, q, s);
#pragma unroll
    for (int mt = 0; mt < 4; ++mt) {
      y2[mt].x += yr[mt].x; y2[mt].y += yr[mt].y;
      y2[mt].z += yr[mt].z; y2[mt].w += yr[mt].w;
    }
    lnorm_c(y2, p.yn2_g, p.yn2_b, q);
#pragma unroll
    for (int mt = 0; mt < 4; ++mt) stc(Yb, S64, mt, q, s, y2[mt]);
  }

  // ---- out = (y @ W_out^T + b_out)[:, 0]
  float acc = 0.f;
#pragma unroll
  for (int mt = 0; mt < 4; ++mt) {
    f32x4 yv = ldc4(Yb, S64, mt, q, s);
    f32x4 w4 = *(const f32x4*)(p.W_out + mt * 16 + q * 4);
    acc += dot4(yv, w4);
  }
  acc += __shfl_xor(acc, 16); acc += __shfl_xor(acc, 32);
  if (q == 0 && (row0 + s) < p.nrows) p.out[row0 + s] = acc + p.b_out[0];
}

extern "C" void kernel_launch(void* const* d_in, const int* in_sizes, int n_in,
                              void* d_out, int out_size, void* d_ws,
                              size_t ws_size, hipStream_t stream) {
  Params p;
  const float* const* in = (const float* const*)d_in;
  p.x        = in[0];  p.W_in     = in[1];  p.b_in     = in[2];
  p.g_in     = in[3];  p.be_in    = in[4];
  p.z_in_w   = in[5];  p.z_in_b   = in[6];
  p.z_out_w  = in[7];  p.z_out_b  = in[8];
  p.z_ffn_w1 = in[9];  p.z_ffn_b1 = in[10];
  p.z_ffn_w2 = in[11]; p.z_ffn_b2 = in[12];
  p.zn1_g    = in[13]; p.zn1_b    = in[14];
  p.zn2_g    = in[15]; p.zn2_b    = in[16];
  p.y_in_w   = in[17]; p.y_in_b   = in[18];
  p.y_out_w  = in[19]; p.y_out_b  = in[20];
  p.y_ffn_w1 = in[21]; p.y_ffn_b1 = in[22];
  p.y_ffn_w2 = in[23]; p.y_ffn_b2 = in[24];
  p.yn1_g    = in[25]; p.yn1_b    = in[26];
  p.yn2_g    = in[27]; p.yn2_b    = in[28];
  p.W_out    = in[29]; p.b_out    = in[30];
  p.out      = (float*)d_out;
  p.nrows    = in_sizes[0] / INDIM;

  if (ws_size < (size_t)NFRAG * 1024) return;  // workspace too small (not expected)
  ushort* wf = (ushort*)d_ws;

  hipLaunchKernelGGL(prepack_kernel, dim3(NFRAG), dim3(64), 0, stream, p, wf);
  int blocks = (p.nrows + 63) / 64;
  hipLaunchKernelGGL(trm_mfma_kernel, dim3(blocks), dim3(256), 0, stream, p, wf);
}

// Round 3
// 1092.985 us; speedup vs baseline: 44.8737x; 4.4056x over previous
//
#include <hip/hip_runtime.h>
#include <math.h>

// ---------------------------------------------------------------------------
// Round 3: all steady-state weights + params staged in LDS; carries in regs.
//   - 112 weight frags (114,688 B) + packed biases/LN params (6,176 B) copied
//     global->LDS once per block; inner loop is LDS+regs only.
//   - K0/V0, z/y residual carries, zres/yres: fp32 registers (no LDS readback).
//   - T/H/XP overlay one region (per-wave DS ops are in-order; reads precede
//     writes in program order).
//   - 512 blocks x 256 thr, 156.7 KB LDS -> 1 block/CU, 4 chunks/block.
// ---------------------------------------------------------------------------

constexpr int STEPS = 16;
constexpr int INDIM = 200;

typedef __attribute__((ext_vector_type(8))) short bfrag8;   // 8 bf16 = 4 VGPR
typedef __attribute__((ext_vector_type(4))) float f32x4;
typedef __attribute__((ext_vector_type(4))) short s16x4;

// ---- global workspace frag indices (prepack output; 1 frag = 512 shorts) ----
constexpr int FB_WIN  = 0;    // W_in: mt(4) x kt(7)
constexpr int FB_ZQ   = 28;
constexpr int FB_ZK   = 36;
constexpr int FB_ZV   = 44;
constexpr int FB_ZOUT = 52;
constexpr int FB_ZF1  = 60;
constexpr int FB_ZF2  = 76;
constexpr int FB_YV   = 92;
constexpr int FB_YOUT = 100;
constexpr int FB_YF1  = 108;
constexpr int FB_YF2  = 124;
constexpr int NFRAG   = 140;
constexpr int NPARAM  = 1544;  // packed fp32 params (padded to x16B)

// ---- LDS-resident steady frag indices (= global index - 28) ----
constexpr int LB_ZQ   = 0;
constexpr int LB_ZK   = 8;
constexpr int LB_ZV   = 16;
constexpr int LB_ZOUT = 24;
constexpr int LB_ZF1  = 32;
constexpr int LB_ZF2  = 48;
constexpr int LB_YV   = 64;
constexpr int LB_YOUT = 72;
constexpr int LB_YF1  = 80;
constexpr int LB_YF2  = 96;
constexpr int NSTEADY = 112;

// ---- packed param float offsets ----
constexpr int PB_BIN   = 0;
constexpr int PB_GIN   = 64;
constexpr int PB_BEIN  = 128;
constexpr int PB_ZINB  = 192;   // 192 floats (q|k|v)
constexpr int PB_ZOUTB = 384;
constexpr int PB_ZF1B  = 448;
constexpr int PB_ZF2B  = 576;
constexpr int PB_ZN1G  = 640;
constexpr int PB_ZN1B  = 704;
constexpr int PB_ZN2G  = 768;
constexpr int PB_ZN2B  = 832;
constexpr int PB_YVB   = 896;   // y_in_b[128..191]
constexpr int PB_YOUTB = 960;
constexpr int PB_YF1B  = 1024;
constexpr int PB_YF2B  = 1152;
constexpr int PB_YN1G  = 1216;
constexpr int PB_YN1B  = 1280;
constexpr int PB_YN2G  = 1344;
constexpr int PB_YN2B  = 1408;
constexpr int PB_WOUT  = 1472;
constexpr int PB_BOUT  = 1536;

// ---- LDS arena layout (shorts) ----
constexpr int S64      = 72;    // activation row stride (64-feat buffers)
constexpr int S128     = 136;   // H row stride
constexpr int L_W      = 0;                       // 112 frags = 57,344 shorts
constexpr int L_P      = 57344;                   // params: 3,088 shorts
constexpr int L_ACT    = 60432;                   // 4 waves x 4480 shorts
constexpr int WAVE_SH  = 4480;                    // Y(1152) Z(1152) TH(2176)
constexpr int AO_Y     = 0;
constexpr int AO_Z     = 1152;
constexpr int AO_TH    = 2304;
constexpr int ARENA_SH = L_ACT + 4 * WAVE_SH;     // 78,352 shorts = 156,704 B

struct Params {
  const float *x, *W_in, *b_in, *g_in, *be_in;
  const float *z_in_w, *z_in_b, *z_out_w, *z_out_b;
  const float *z_ffn_w1, *z_ffn_b1, *z_ffn_w2, *z_ffn_b2;
  const float *zn1_g, *zn1_b, *zn2_g, *zn2_b;
  const float *y_in_w, *y_in_b, *y_out_w, *y_out_b;
  const float *y_ffn_w1, *y_ffn_b1, *y_ffn_w2, *y_ffn_b2;
  const float *yn1_g, *yn1_b, *yn2_g, *yn2_b;
  const float *W_out, *b_out;
  float *out;
  int nrows;
};

__device__ __forceinline__ ushort f2bf(float f) {
  uint u = __float_as_uint(f);
  u += 0x7FFFu + ((u >> 16) & 1u);
  return (ushort)(u >> 16);
}
__device__ __forceinline__ float dot4(f32x4 a, f32x4 b) {
  return a.x * b.x + a.y * b.y + a.z * b.z + a.w * b.w;
}
__device__ __forceinline__ void stc(short* buf, int stride, int mt, int q,
                                    int s, f32x4 c) {
  s16x4 v;
  v.x = (short)f2bf(c.x); v.y = (short)f2bf(c.y);
  v.z = (short)f2bf(c.z); v.w = (short)f2bf(c.w);
  *(s16x4*)(buf + s * stride + mt * 16 + q * 4) = v;
}

// c[mt] = W * X^T + bias; A-frags and bias from LDS.
template <int MT, int KT>
__device__ __forceinline__ void layerN(const short* in, int stride,
                                       const short* lw, int fbase,
                                       const float* bias, f32x4* c,
                                       int lane, int q, int s) {
  bfrag8 bf[KT];
#pragma unroll
  for (int kt = 0; kt < KT; ++kt)
    bf[kt] = *(const bfrag8*)(in + s * stride + kt * 32 + q * 8);
#pragma unroll
  for (int mt = 0; mt < MT; ++mt)
    c[mt] = *(const f32x4*)(bias + mt * 16 + q * 4);
#pragma unroll
  for (int mt = 0; mt < MT; ++mt) {
#pragma unroll
    for (int kt = 0; kt < KT; ++kt) {
      bfrag8 af = *(const bfrag8*)(lw + (fbase + mt * KT + kt) * 512 + lane * 8);
      c[mt] = __builtin_amdgcn_mfma_f32_16x16x32_bf16(af, bf[kt], c[mt], 0, 0, 0);
    }
  }
}

__device__ __forceinline__ void lnorm_c(f32x4 c[4], const float* g,
                                        const float* b, int q) {
  float sm = 0.f;
#pragma unroll
  for (int mt = 0; mt < 4; ++mt) sm += c[mt].x + c[mt].y + c[mt].z + c[mt].w;
  sm += __shfl_xor(sm, 16); sm += __shfl_xor(sm, 32);
  float mean = sm * (1.f / 64.f);
  float vs = 0.f;
#pragma unroll
  for (int mt = 0; mt < 4; ++mt) {
    f32x4 d = c[mt];
    d.x -= mean; d.y -= mean; d.z -= mean; d.w -= mean;
    c[mt] = d;
    vs += d.x * d.x + d.y * d.y + d.z * d.z + d.w * d.w;
  }
  vs += __shfl_xor(vs, 16); vs += __shfl_xor(vs, 32);
  float rs = rsqrtf(vs * (1.f / 64.f) + 1e-5f);
#pragma unroll
  for (int mt = 0; mt < 4; ++mt) {
    f32x4 g4 = *(const f32x4*)(g + mt * 16 + q * 4);
    f32x4 b4 = *(const f32x4*)(b + mt * 16 + q * 4);
    f32x4 v = c[mt];
    v.x = v.x * rs * g4.x + b4.x; v.y = v.y * rs * g4.y + b4.y;
    v.z = v.z * rs * g4.z + b4.z; v.w = v.w * rs * g4.w + b4.w;
    c[mt] = v;
  }
}

__device__ __forceinline__ float gelu1(float x) {
  float ax = fabsf(x) * 0.70710678118654752f;
  float t = __builtin_amdgcn_rcpf(1.0f + 0.3275911f * ax);
  float poly =
      ((((1.061405429f * t - 1.453152027f) * t + 1.421413741f) * t -
        0.284496736f) * t + 0.254829592f) * t;
  float e = __expf(-ax * ax);
  float erfv = copysignf(1.0f - poly * e, x);
  return 0.5f * x * (1.0f + erfv);
}

// ---------------------------------------------------------------------------
// prepack: weights -> A-frag bf16 order; params -> packed fp32 array
// ---------------------------------------------------------------------------
__global__ void prepack_kernel(Params p, ushort* wf) {
  int f = blockIdx.x;
  int lane = threadIdx.x;

  if (f == NFRAG) {  // param packer
    float* pw = (float*)(wf + (size_t)NFRAG * 512);
    for (int t = lane; t < NPARAM; t += 64) {
      float v = 0.f;
      if      (t < 64)   v = p.b_in[t];
      else if (t < 128)  v = p.g_in[t - 64];
      else if (t < 192)  v = p.be_in[t - 128];
      else if (t < 384)  v = p.z_in_b[t - 192];
      else if (t < 448)  v = p.z_out_b[t - 384];
      else if (t < 576)  v = p.z_ffn_b1[t - 448];
      else if (t < 640)  v = p.z_ffn_b2[t - 576];
      else if (t < 704)  v = p.zn1_g[t - 640];
      else if (t < 768)  v = p.zn1_b[t - 704];
      else if (t < 832)  v = p.zn2_g[t - 768];
      else if (t < 896)  v = p.zn2_b[t - 832];
      else if (t < 960)  v = p.y_in_b[128 + t - 896];
      else if (t < 1024) v = p.y_out_b[t - 960];
      else if (t < 1152) v = p.y_ffn_b1[t - 1024];
      else if (t < 1216) v = p.y_ffn_b2[t - 1152];
      else if (t < 1280) v = p.yn1_g[t - 1216];
      else if (t < 1344) v = p.yn1_b[t - 1280];
      else if (t < 1408) v = p.yn2_g[t - 1344];
      else if (t < 1472) v = p.yn2_b[t - 1408];
      else if (t < 1536) v = p.W_out[t - 1472];
      else if (t == 1536) v = p.b_out[0];
      pw[t] = v;
    }
    return;
  }

  int q = lane >> 4, r = lane & 15;
  const float* src; int K, mt, kt, l;
  if (f < 28)        { src = p.W_in;                K = 200; mt = f / 7;  kt = f % 7; }
  else if (f < 36)   { l = f - 28;  src = p.z_in_w;            K = 64;  mt = l / 2; kt = l % 2; }
  else if (f < 44)   { l = f - 36;  src = p.z_in_w + 64 * 64;  K = 64;  mt = l / 2; kt = l % 2; }
  else if (f < 52)   { l = f - 44;  src = p.z_in_w + 128 * 64; K = 64;  mt = l / 2; kt = l % 2; }
  else if (f < 60)   { l = f - 52;  src = p.z_out_w;           K = 64;  mt = l / 2; kt = l % 2; }
  else if (f < 76)   { l = f - 60;  src = p.z_ffn_w1;          K = 64;  mt = l / 2; kt = l % 2; }
  else if (f < 92)   { l = f - 76;  src = p.z_ffn_w2;          K = 128; mt = l / 4; kt = l % 4; }
  else if (f < 100)  { l = f - 92;  src = p.y_in_w + 128 * 64; K = 64;  mt = l / 2; kt = l % 2; }
  else if (f < 108)  { l = f - 100; src = p.y_out_w;           K = 64;  mt = l / 2; kt = l % 2; }
  else if (f < 124)  { l = f - 108; src = p.y_ffn_w1;          K = 64;  mt = l / 2; kt = l % 2; }
  else               { l = f - 124; src = p.y_ffn_w2;          K = 128; mt = l / 4; kt = l % 4; }

  int row = mt * 16 + r;
  int col = kt * 32 + q * 8;
  bfrag8 o;
#pragma unroll
  for (int j = 0; j < 8; ++j) {
    int cc = col + j;
    float v = (cc < K) ? src[(size_t)row * K + cc] : 0.0f;
    o[j] = (short)f2bf(v);
  }
  *(bfrag8*)(wf + (size_t)f * 512 + lane * 8) = o;
}

// ---------------------------------------------------------------------------
// main kernel: 1 block/CU, weights in LDS, carries in registers
// ---------------------------------------------------------------------------
__global__ __launch_bounds__(256, 1) void trm_mfma_kernel(Params p,
                                                          const ushort* wf) {
  __shared__ __align__(16) short arena[ARENA_SH];
  const int tid = threadIdx.x;
  const int wave = tid >> 6, lane = tid & 63;
  const int q = lane >> 4, s = lane & 15;

  // ---- stage steady weights + params into LDS (once per block) ----
  {
    const uint4* srcw = (const uint4*)(wf + (size_t)28 * 512);
    uint4* dstw = (uint4*)(arena + L_W);
    for (int i = tid; i < NSTEADY * 64; i += 256) dstw[i] = srcw[i];
    const uint4* srcp = (const uint4*)(wf + (size_t)NFRAG * 512);
    uint4* dstp = (uint4*)(arena + L_P);
    for (int i = tid; i < NPARAM / 4; i += 256) dstp[i] = srcp[i];
  }
  __syncthreads();  // the only barrier

  const short* LW = arena + L_W;
  const float* P  = (const float*)(arena + L_P);
  short* WA = arena + L_ACT + wave * WAVE_SH;
  short *Yb = WA + AO_Y, *Zb = WA + AO_Z, *TH = WA + AO_TH;

  const int chunks = (p.nrows + 63) / 64;
  for (int ic = blockIdx.x; ic < chunks; ic += gridDim.x) {
    const int row0 = ic * 64 + wave * 16;
    int row = row0 + s;
    if (row >= p.nrows) row = p.nrows - 1;

    // ---- x_proj = gelu(ln(x @ W_in^T + b_in)); A-frags from global wf ----
    {
      const float* xr = p.x + (size_t)row * INDIM;
      bfrag8 xb[7];
#pragma unroll
      for (int kt = 0; kt < 7; ++kt) {
        int k0i = kt * 32 + q * 8;
        bfrag8 t;
        if (kt < 6 || q == 0) {
          f32x4 lo = *(const f32x4*)(xr + k0i);
          f32x4 hi = *(const f32x4*)(xr + k0i + 4);
          t[0] = (short)f2bf(lo.x); t[1] = (short)f2bf(lo.y);
          t[2] = (short)f2bf(lo.z); t[3] = (short)f2bf(lo.w);
          t[4] = (short)f2bf(hi.x); t[5] = (short)f2bf(hi.y);
          t[6] = (short)f2bf(hi.z); t[7] = (short)f2bf(hi.w);
        } else {
#pragma unroll
          for (int j = 0; j < 8; ++j) t[j] = 0;
        }
        xb[kt] = t;
      }
      f32x4 c[4];
#pragma unroll
      for (int mt = 0; mt < 4; ++mt)
        c[mt] = *(const f32x4*)(P + PB_BIN + mt * 16 + q * 4);
#pragma unroll
      for (int mt = 0; mt < 4; ++mt)
#pragma unroll
        for (int kt = 0; kt < 7; ++kt) {
          bfrag8 af =
              *(const bfrag8*)(wf + (size_t)(FB_WIN + mt * 7 + kt) * 512 + lane * 8);
          c[mt] = __builtin_amdgcn_mfma_f32_16x16x32_bf16(af, xb[kt], c[mt], 0, 0, 0);
        }
      lnorm_c(c, P + PB_GIN, P + PB_BEIN, q);
#pragma unroll
      for (int mt = 0; mt < 4; ++mt) {
        c[mt].x = gelu1(c[mt].x); c[mt].y = gelu1(c[mt].y);
        c[mt].z = gelu1(c[mt].z); c[mt].w = gelu1(c[mt].w);
        stc(TH, S64, mt, q, s, c[mt]);  // XP lives in TH region
      }
    }

    // ---- k0/v0 in registers; zero y/z ----
    f32x4 k0r[4], v0r[4], zC[4], yC[4];
    layerN<4, 2>(TH, S64, LW, LB_ZK, P + PB_ZINB + 64, k0r, lane, q, s);
    layerN<4, 2>(TH, S64, LW, LB_ZV, P + PB_ZINB + 128, v0r, lane, q, s);
    {
      s16x4 z4; z4.x = 0; z4.y = 0; z4.z = 0; z4.w = 0;
      f32x4 zf; zf.x = 0.f; zf.y = 0.f; zf.z = 0.f; zf.w = 0.f;
#pragma unroll
      for (int mt = 0; mt < 4; ++mt) {
        *(s16x4*)(Yb + s * S64 + mt * 16 + q * 4) = z4;
        *(s16x4*)(Zb + s * S64 + mt * 16 + q * 4) = z4;
        zC[mt] = zf; yC[mt] = zf;
      }
    }

    // ---- 16 recursive steps (LDS + registers only) ----
    for (int st = 0; st < STEPS; ++st) {
      f32x4 q2[4], k2[4], v2[4], k1[4], v1[4];
      layerN<4, 2>(Zb, S64, LW, LB_ZQ, P + PB_ZINB, q2, lane, q, s);
      layerN<4, 2>(Zb, S64, LW, LB_ZK, P + PB_ZINB + 64, k2, lane, q, s);
      layerN<4, 2>(Zb, S64, LW, LB_ZV, P + PB_ZINB + 128, v2, lane, q, s);
      layerN<4, 2>(Yb, S64, LW, LB_ZK, P + PB_ZINB + 64, k1, lane, q, s);
      layerN<4, 2>(Yb, S64, LW, LB_ZV, P + PB_ZINB + 128, v1, lane, q, s);

#pragma unroll
      for (int mt = 0; mt < 4; ++mt) {
        float a0 = dot4(q2[mt], k0r[mt]);
        float a1 = dot4(q2[mt], k1[mt]);
        float a2 = dot4(q2[mt], k2[mt]);
        a0 += __shfl_xor(a0, 16); a0 += __shfl_xor(a0, 32);
        a1 += __shfl_xor(a1, 16); a1 += __shfl_xor(a1, 32);
        a2 += __shfl_xor(a2, 16); a2 += __shfl_xor(a2, 32);
        a0 *= 0.25f; a1 *= 0.25f; a2 *= 0.25f;
        float mx = fmaxf(a0, fmaxf(a1, a2));
        float e0 = __expf(a0 - mx), e1 = __expf(a1 - mx), e2 = __expf(a2 - mx);
        float inv = __builtin_amdgcn_rcpf(e0 + e1 + e2);
        f32x4 o;
        o.x = (v0r[mt].x * e0 + v1[mt].x * e1 + v2[mt].x * e2) * inv;
        o.y = (v0r[mt].y * e0 + v1[mt].y * e1 + v2[mt].y * e2) * inv;
        o.z = (v0r[mt].z * e0 + v1[mt].z * e1 + v2[mt].z * e2) * inv;
        o.w = (v0r[mt].w * e0 + v1[mt].w * e1 + v2[mt].w * e2) * inv;
        stc(TH, S64, mt, q, s, o);
      }

      // z branch
      f32x4 zr[4];
      layerN<4, 2>(TH, S64, LW, LB_ZOUT, P + PB_ZOUTB, zr, lane, q, s);
#pragma unroll
      for (int mt = 0; mt < 4; ++mt) {
        zr[mt].x += zC[mt].x; zr[mt].y += zC[mt].y;
        zr[mt].z += zC[mt].z; zr[mt].w += zC[mt].w;
      }
      lnorm_c(zr, P + PB_ZN1G, P + PB_ZN1B, q);
#pragma unroll
      for (int mt = 0; mt < 4; ++mt) stc(TH, S64, mt, q, s, zr[mt]);

      f32x4 h8[8];
      layerN<8, 2>(TH, S64, LW, LB_ZF1, P + PB_ZF1B, h8, lane, q, s);
#pragma unroll
      for (int mt = 0; mt < 8; ++mt) {
        h8[mt].x = gelu1(h8[mt].x); h8[mt].y = gelu1(h8[mt].y);
        h8[mt].z = gelu1(h8[mt].z); h8[mt].w = gelu1(h8[mt].w);
        stc(TH, S128, mt, q, s, h8[mt]);
      }
      f32x4 z2[4];
      layerN<4, 4>(TH, S128, LW, LB_ZF2, P + PB_ZF2B, z2, lane, q, s);
#pragma unroll
      for (int mt = 0; mt < 4; ++mt) {
        z2[mt].x += zr[mt].x; z2[mt].y += zr[mt].y;
        z2[mt].z += zr[mt].z; z2[mt].w += zr[mt].w;
      }
      lnorm_c(z2, P + PB_ZN2G, P + PB_ZN2B, q);
#pragma unroll
      for (int mt = 0; mt < 4; ++mt) {
        zC[mt] = z2[mt];
        stc(Zb, S64, mt, q, s, z2[mt]);
      }

      // y branch
      f32x4 t4[4];
      layerN<4, 2>(Zb, S64, LW, LB_YV, P + PB_YVB, t4, lane, q, s);
#pragma unroll
      for (int mt = 0; mt < 4; ++mt) stc(TH, S64, mt, q, s, t4[mt]);

      f32x4 yr[4];
      layerN<4, 2>(TH, S64, LW, LB_YOUT, P + PB_YOUTB, yr, lane, q, s);
#pragma unroll
      for (int mt = 0; mt < 4; ++mt) {
        yr[mt].x += yC[mt].x; yr[mt].y += yC[mt].y;
        yr[mt].z += yC[mt].z; yr[mt].w += yC[mt].w;
      }
      lnorm_c(yr, P + PB_YN1G, P + PB_YN1B, q);
#pragma unroll
      for (int mt = 0; mt < 4; ++mt) stc(TH, S64, mt, q, s, yr[mt]);

      layerN<8, 2>(TH, S64, LW, LB_YF1, P + PB_YF1B, h8, lane, q, s);
#pragma unroll
      for (int mt = 0; mt < 8; ++mt) {
        h8[mt].x = gelu1(h8[mt].x); h8[mt].y = gelu1(h8[mt].y);
        h8[mt].z = gelu1(h8[mt].z); h8[mt].w = gelu1(h8[mt].w);
        stc(TH, S128, mt, q, s, h8[mt]);
      }
      f32x4 y2[4];
      layerN<4, 4>(TH, S128, LW, LB_YF2, P + PB_YF2B, y2, lane, q, s);
#pragma unroll
      for (int mt = 0; mt < 4; ++mt) {
        y2[mt].x += yr[mt].x; y2[mt].y += yr[mt].y;
        y2[mt].z += yr[mt].z; y2[mt].w += yr[mt].w;
      }
      lnorm_c(y2, P + PB_YN2G, P + PB_YN2B, q);
#pragma unroll
      for (int mt = 0; mt < 4; ++mt) {
        yC[mt] = y2[mt];
        stc(Yb, S64, mt, q, s, y2[mt]);
      }
    }

    // ---- out = (y @ W_out^T + b_out)[:, 0] from registers ----
    float acc = 0.f;
#pragma unroll
    for (int mt = 0; mt < 4; ++mt) {
      f32x4 w4 = *(const f32x4*)(P + PB_WOUT + mt * 16 + q * 4);
      acc += dot4(yC[mt], w4);
    }
    acc += __shfl_xor(acc, 16); acc += __shfl_xor(acc, 32);
    if (q == 0 && (row0 + s) < p.nrows) p.out[row0 + s] = acc + P[PB_BOUT];
  }
}

extern "C" void kernel_launch(void* const* d_in, const int* in_sizes, int n_in,
                              void* d_out, int out_size, void* d_ws,
                              size_t ws_size, hipStream_t stream) {
  Params p;
  const float* const* in = (const float* const*)d_in;
  p.x        = in[0];  p.W_in     = in[1];  p.b_in     = in[2];
  p.g_in     = in[3];  p.be_in    = in[4];
  p.z_in_w   = in[5];  p.z_in_b   = in[6];
  p.z_out_w  = in[7];  p.z_out_b  = in[8];
  p.z_ffn_w1 = in[9];  p.z_ffn_b1 = in[10];
  p.z_ffn_w2 = in[11]; p.z_ffn_b2 = in[12];
  p.zn1_g    = in[13]; p.zn1_b    = in[14];
  p.zn2_g    = in[15]; p.zn2_b    = in[16];
  p.y_in_w   = in[17]; p.y_in_b   = in[18];
  p.y_out_w  = in[19]; p.y_out_b  = in[20];
  p.y_ffn_w1 = in[21]; p.y_ffn_b1 = in[22];
  p.y_ffn_w2 = in[23]; p.y_ffn_b2 = in[24];
  p.yn1_g    = in[25]; p.yn1_b    = in[26];
  p.yn2_g    = in[27]; p.yn2_b    = in[28];
  p.W_out    = in[29]; p.b_out    = in[30];
  p.out      = (float*)d_out;
  p.nrows    = in_sizes[0] / INDIM;

  if (ws_size < (size_t)NFRAG * 1024 + NPARAM * 4) return;
  ushort* wf = (ushort*)d_ws;

  hipLaunchKernelGGL(prepack_kernel, dim3(NFRAG + 1), dim3(64), 0, stream, p, wf);
  hipLaunchKernelGGL(trm_mfma_kernel, dim3(512), dim3(256), 0, stream, p, wf);
}